// Round 1
// 483.500 us; speedup vs baseline: 1.0863x; 1.0863x over previous
//
#include <hip/hip_runtime.h>
#include <hip/hip_bf16.h>

#define EPSV 1e-5f
#define PSHIFT 6            // partition = 64 nodes
#define PMASK 63
#define PCAP 1536           // per-partition staging cap (mean 1024, +16 sigma)
#define B1SHIFT 11          // coarse bucket = 2048 nodes = 32 partitions
#define B1MASK ((1 << B1SHIFT) - 1)
#define B1CAP 34816         // per-bucket cap (mean 32768, +11 sigma)
#define SPLIT 16            // scatter2 blocks per coarse bucket

typedef __attribute__((ext_vector_type(8))) short bf16x8;
typedef __attribute__((ext_vector_type(4))) float f32x4;

__device__ __forceinline__ float bf2f(unsigned short u) {
    unsigned x = ((unsigned)u) << 16;
    return __builtin_bit_cast(float, x);
}
__device__ __forceinline__ unsigned short f2bf(float f) {
    unsigned x = __builtin_bit_cast(unsigned, f);
    unsigned r = (x + 0x7fffu + ((x >> 16) & 1u)) >> 16;  // RNE
    return (unsigned short)r;
}

// ---------------- two-level LDS-ranked scatter (R8) ----------------
// R7's k_bucket: per-edge device-scope atomicAdd + dependent scattered 4B store
// -> latency-bound (VALU 0.8%, HBM 10%), WRITE_SIZE 51 MB for 6.4 MB payload.
// R8: LDS histogram + block-level reservation. Global atomics: 1.6M -> 63K.
// Writes become ~167-512B contiguous runs -> ~1x writeback amplification.

// level 1: edges -> 49 coarse buckets (2048 nodes each). val=(s<<11)|(d&2047).
__global__ __launch_bounds__(256) void k_scatter1(const int* __restrict__ src,
                                                  const int* __restrict__ dst,
                                                  int* __restrict__ bcnt1,
                                                  unsigned* __restrict__ stg1,
                                                  int E, int NB1) {
    __shared__ int hist[64], sbase[64], scur[64];
    int t = threadIdx.x;
    int base = blockIdx.x * 2048;
    if (t < 64) { hist[t] = 0; scur[t] = 0; }
    __syncthreads();
    unsigned val[8];
    int cb[8];
#pragma unroll
    for (int k = 0; k < 8; k++) {
        int i = base + k * 256 + t;
        if (i < E) {
            int d = __builtin_nontemporal_load(&dst[i]);
            int s = __builtin_nontemporal_load(&src[i]);
            cb[k] = d >> B1SHIFT;
            val[k] = ((unsigned)s << B1SHIFT) | (unsigned)(d & B1MASK);
            atomicAdd(&hist[cb[k]], 1);
        } else
            cb[k] = -1;
    }
    __syncthreads();
    if (t < NB1 && hist[t] > 0) sbase[t] = atomicAdd(&bcnt1[t], hist[t]);
    __syncthreads();
#pragma unroll
    for (int k = 0; k < 8; k++) {
        if (cb[k] >= 0) {
            int r = atomicAdd(&scur[cb[k]], 1);
            int slot = sbase[cb[k]] + r;
            if (slot < B1CAP) stg1[(size_t)cb[k] * B1CAP + slot] = val[k];
        }
    }
}

// level 2: coarse bucket -> 32 partitions inside it. out val=(s<<6)|(d&63).
__global__ __launch_bounds__(256) void k_scatter2(const int* __restrict__ bcnt1,
                                                  const unsigned* __restrict__ stg1,
                                                  int* __restrict__ pcnt,
                                                  unsigned* __restrict__ pstg) {
    __shared__ int hist[32], sbase[32], scur[32];
    int cb = blockIdx.x >> 4;  // / SPLIT
    int sl = blockIdx.x & (SPLIT - 1);
    int t = threadIdx.x;
    if (t < 32) { hist[t] = 0; scur[t] = 0; }
    int cnt = min(bcnt1[cb], B1CAP);
    int per = (cnt + SPLIT - 1) / SPLIT;
    int lo = sl * per, hi = min(lo + per, cnt);
    __syncthreads();
    const unsigned* sp = stg1 + (size_t)cb * B1CAP;
    for (int j = lo + t; j < hi; j += 256)
        atomicAdd(&hist[(sp[j] >> 6) & 31], 1);
    __syncthreads();
    if (t < 32 && hist[t] > 0) sbase[t] = atomicAdd(&pcnt[(cb << 5) + t], hist[t]);
    __syncthreads();
    for (int j = lo + t; j < hi; j += 256) {
        unsigned v = sp[j];
        int pr = (v >> 6) & 31;  // d bits 6..10 = partition within bucket
        int r = atomicAdd(&scur[pr], 1);
        int slot = sbase[pr] + r;
        if (slot < PCAP)
            pstg[(size_t)((cb << 5) + pr) * PCAP + slot] =
                ((v >> 5) & ~63u) | (v & 63u);  // (s<<6)|(d&63)
    }
}

// block 0: partition totals + exclusive scan -> pbase, off[N]=total
// block 1: graph bounds from sorted batch (binary search)
__global__ __launch_bounds__(256) void k_meta(const int* __restrict__ pcnt,
                                              int* __restrict__ pbase,
                                              int* __restrict__ off,
                                              const int* __restrict__ batch,
                                              int* __restrict__ gstart,
                                              int NPART, int Nn, int G) {
    if (blockIdx.x == 1) {
        int g = threadIdx.x;
        if (g > G) return;
        if (g == G) {
            gstart[G] = Nn;
            return;
        }
        int lo = 0, hi = Nn;
        while (lo < hi) {
            int mid = (lo + hi) >> 1;
            if (batch[mid] < g) lo = mid + 1;
            else hi = mid;
        }
        gstart[g] = lo;
        return;
    }
    __shared__ int red[256];
    int t = threadIdx.x;
    int chunk = (NPART + 255) / 256;
    int lo = t * chunk, hi = min(lo + chunk, NPART);
    int s = 0;
    for (int p = lo; p < hi; p++) {
        int tt = min(pcnt[p], PCAP);
        pbase[p] = tt;  // temp: totals
        s += tt;
    }
    red[t] = s;
    __syncthreads();
    for (int d = 1; d < 256; d <<= 1) {
        int v = (t >= d) ? red[t - d] : 0;
        __syncthreads();
        red[t] += v;
        __syncthreads();
    }
    int base = (t == 0) ? 0 : red[t - 1];
    for (int p = lo; p < hi; p++) {
        int tt = pbase[p];
        pbase[p] = base;
        base += tt;
    }
    if (t == 255) off[Nn] = red[255];
}

__global__ __launch_bounds__(256) void k_build(const int* __restrict__ pcnt,
                                               const unsigned* __restrict__ pstg,
                                               const int* __restrict__ pbase,
                                               int* __restrict__ off,
                                               int* __restrict__ csr, int Nn) {
    __shared__ unsigned ed[PCAP];
    __shared__ int srt[PCAP];
    __shared__ int cnt[64], loff[64], cur[64];
    int p = blockIdx.x, t = threadIdx.x;
    int tot = min(pcnt[p], PCAP);
    if (t < 64) cnt[t] = 0;
    __syncthreads();
    const unsigned* sp = pstg + (size_t)p * PCAP;
    for (int j = t; j < tot; j += 256) {
        unsigned e = __builtin_nontemporal_load(&sp[j]);
        ed[j] = e;
        atomicAdd(&cnt[e & PMASK], 1);
    }
    __syncthreads();
    if (t == 0) {
        int a = 0;
        for (int j = 0; j < 64; j++) {
            loff[j] = a;
            cur[j] = a;
            a += cnt[j];
        }
    }
    __syncthreads();
    int base = pbase[p];
    int node0 = p << PSHIFT;
    if (t < 64 && node0 + t < Nn) off[node0 + t] = base + loff[t];
    for (int j = t; j < tot; j += 256) {
        unsigned e = ed[j];
        int pos = atomicAdd(&cur[e & PMASK], 1);
        srt[pos] = (int)(e >> PSHIFT);
    }
    __syncthreads();
    for (int j = t; j < tot; j += 256) csr[base + j] = srt[j];
}

// ---------------- aggregation ----------------

__global__ __launch_bounds__(256) void k_agg7(const float* __restrict__ x,
                                              const int* __restrict__ off,
                                              const int* __restrict__ csr,
                                              float* __restrict__ mean, int n) {
    int i = (blockIdx.x * 256 + threadIdx.x) >> 3;
    int r = threadIdx.x & 7;
    if (i >= n) return;
    int a = off[i], b = off[i + 1];
    float acc = 0.f;
    if (r < 7) {
        int j = a;
        for (; j + 1 < b; j += 2)
            acc += x[(size_t)csr[j] * 7 + r] + x[(size_t)csr[j + 1] * 7 + r];
        if (j < b) acc += x[(size_t)csr[j] * 7 + r];
    }
    float inv = 1.0f / (float)max(b - a, 1);
    if (r < 7) mean[(size_t)i * 7 + r] = acc * inv;
}

__global__ __launch_bounds__(256) void k_agg128(const unsigned short* __restrict__ x,
                                                const int* __restrict__ off,
                                                const int* __restrict__ csr,
                                                unsigned short* __restrict__ mean,
                                                int n) {
    int h = (blockIdx.x * 256 + threadIdx.x) >> 5;  // half-wave = node
    int sl = threadIdx.x & 31;
    if (h >= n) return;
    int a = off[h], b = off[h + 1];
    float a0 = 0.f, a1 = 0.f, a2 = 0.f, a3 = 0.f;
    int j = a;
    for (; j + 3 < b; j += 4) {
        int s0 = csr[j], s1 = csr[j + 1], s2 = csr[j + 2], s3 = csr[j + 3];
        ushort4 v0 = *(const ushort4*)&x[(size_t)s0 * 128 + sl * 4];
        ushort4 v1 = *(const ushort4*)&x[(size_t)s1 * 128 + sl * 4];
        ushort4 v2 = *(const ushort4*)&x[(size_t)s2 * 128 + sl * 4];
        ushort4 v3 = *(const ushort4*)&x[(size_t)s3 * 128 + sl * 4];
        a0 += bf2f(v0.x) + bf2f(v1.x) + bf2f(v2.x) + bf2f(v3.x);
        a1 += bf2f(v0.y) + bf2f(v1.y) + bf2f(v2.y) + bf2f(v3.y);
        a2 += bf2f(v0.z) + bf2f(v1.z) + bf2f(v2.z) + bf2f(v3.z);
        a3 += bf2f(v0.w) + bf2f(v1.w) + bf2f(v2.w) + bf2f(v3.w);
    }
    for (; j < b; j++) {
        ushort4 v = *(const ushort4*)&x[(size_t)csr[j] * 128 + sl * 4];
        a0 += bf2f(v.x);
        a1 += bf2f(v.y);
        a2 += bf2f(v.z);
        a3 += bf2f(v.w);
    }
    float inv = 1.0f / (float)max(b - a, 1);
    ushort4 o;
    o.x = f2bf(a0 * inv);
    o.y = f2bf(a1 * inv);
    o.z = f2bf(a2 * inv);
    o.w = f2bf(a3 * inv);
    *(ushort4*)&mean[(size_t)h * 128 + sl * 4] = o;
}

// ---------------- weight prep: all 4 matrices in one launch ----------------
// seg layout (elements): [0,16384) Wl1, [16384,32768) Wr1,
// [32768,65536) Wl2, [65536,98304) Wr2. fp32 [K][N] -> bf16 [N][K].

__global__ __launch_bounds__(256) void k_prepw_all(
    const float* __restrict__ Wl1, const float* __restrict__ Wr1,
    const float* __restrict__ Wl2, const float* __restrict__ Wr2,
    unsigned short* __restrict__ Wlt1, unsigned short* __restrict__ Wrt1,
    unsigned short* __restrict__ Wlt2, unsigned short* __restrict__ Wrt2) {
    int u = blockIdx.x * 256 + threadIdx.x;
    const float* W;
    unsigned short* Wt;
    int Ncols, v;
    if (u < 32768) {
        v = u & 16383;
        W = (u < 16384) ? Wl1 : Wr1;
        Wt = (u < 16384) ? Wlt1 : Wrt1;
        Ncols = 128;
    } else {
        v = (u - 32768) & 32767;
        W = (u < 65536) ? Wl2 : Wr2;
        Wt = (u < 65536) ? Wlt2 : Wrt2;
        Ncols = 256;
    }
    int n = v % Ncols, k = v / Ncols;
    Wt[(size_t)n * 128 + k] = f2bf(W[(size_t)k * Ncols + n]);
}

// ---------------- layer 0 (din=7, fp32 vector) -> bf16 out ----------------

__global__ __launch_bounds__(256) void k_layer0(
    const float* __restrict__ x, const float* __restrict__ mean,
    const float* __restrict__ Wl, const float* __restrict__ bl,
    const float* __restrict__ Wr, const float* __restrict__ g,
    const float* __restrict__ be, const float* __restrict__ rm,
    const float* __restrict__ rv, unsigned short* __restrict__ out, int n) {
    int tid = threadIdx.x;
    int col = tid & 127;
    int r = tid >> 7;
    int row = blockIdx.x * 2 + r;
    if (row >= n) return;
    float sc = g[col] * rsqrtf(rv[col] + EPSV);
    float sh = (bl[col] - rm[col]) * sc + be[col];
    const float* xp = x + (size_t)row * 7;
    const float* mp = mean + (size_t)row * 7;
    float acc = 0.f;
#pragma unroll
    for (int k = 0; k < 7; k++) acc += xp[k] * Wl[k * 128 + col];
#pragma unroll
    for (int k = 0; k < 7; k++) acc += mp[k] * Wr[k * 128 + col];
    float h = acc * sc + sh;
    out[(size_t)row * 128 + col] = f2bf(fmaxf(h, 0.f));
}

// ---------------- MFMA layer (K = 2x128, bf16 inputs, fp32 accum) ----------------
// 64 rows x COLS(=128) per block, 16 rows/wave, acc = 8 x f32x4 = 32 VGPRs,
// LDS 15 KB -> ~6 blocks/CU. Layer 1: COLS=DOUT=128, grid.y=1 (in-place safe).
// Layer 2: COLS=128, grid.y=2 (x3 output disjoint from inputs).

template <int COLS, int DOUT, bool BF16OUT>
__global__ __launch_bounds__(256) void k_mfma_layer(
    const unsigned short* __restrict__ xin, const unsigned short* __restrict__ meanb,
    const unsigned short* __restrict__ Wlt, const unsigned short* __restrict__ Wrt,
    const float* __restrict__ bl, const float* __restrict__ g,
    const float* __restrict__ be, const float* __restrict__ rm,
    const float* __restrict__ rv, void* __restrict__ outv, int n) {
    __shared__ unsigned short As[64 * 40];
    __shared__ unsigned short Bs[COLS * 40];

    int tid = threadIdx.x;
    int wave = tid >> 6;
    int lane = tid & 63;
    int m = lane & 15;
    int half = lane >> 4;
    int row0 = blockIdx.x * 64;
    int colbase = blockIdx.y * COLS;

    const int NCB = COLS / 16;
    f32x4 acc[NCB] = {};

    for (int s = 0; s < 8; s++) {
        int pass = s >> 2;
        int k0 = (s & 3) * 32;
        const unsigned short* Asrc = pass ? meanb : xin;
        const unsigned short* Wt = pass ? Wrt : Wlt;

        __syncthreads();
        {   // stage A: 64 rows x 32 k
            int rr = tid >> 2;
            int ks = (tid & 3) * 8;
            int grow = row0 + rr;
            float4 v = make_float4(0.f, 0.f, 0.f, 0.f);
            if (grow < n) v = *(const float4*)&Asrc[(size_t)grow * 128 + k0 + ks];
            *(float4*)&As[rr * 40 + ks] = v;
        }
#pragma unroll
        for (int rep = 0; rep < COLS / 64; rep++) {  // stage B: COLS cols x 32 k
            int u = tid + rep * 256;
            int nn = u >> 2;
            int ks = (u & 3) * 8;
            float4 v = *(const float4*)&Wt[(size_t)(colbase + nn) * 128 + k0 + ks];
            *(float4*)&Bs[nn * 40 + ks] = v;
        }
        __syncthreads();

        bf16x8 a = *(const bf16x8*)&As[(wave * 16 + m) * 40 + half * 8];
#pragma unroll
        for (int cb = 0; cb < NCB; cb++) {
            bf16x8 b = *(const bf16x8*)&Bs[(cb * 16 + m) * 40 + half * 8];
            acc[cb] = __builtin_amdgcn_mfma_f32_16x16x32_bf16(a, b, acc[cb], 0, 0, 0);
        }
    }

    float* outf = (float*)outv;
    unsigned short* outb = (unsigned short*)outv;
#pragma unroll
    for (int cb = 0; cb < NCB; cb++) {
        int col = colbase + cb * 16 + m;
        float sc = g[col] * rsqrtf(rv[col] + EPSV);
        float sh = (bl[col] - rm[col]) * sc + be[col];
#pragma unroll
        for (int reg = 0; reg < 4; reg++) {
            int r0 = row0 + wave * 16 + half * 4 + reg;
            if (r0 < n) {
                float h = fmaxf(acc[cb][reg] * sc + sh, 0.f);
                if (BF16OUT) outb[(size_t)r0 * DOUT + col] = f2bf(h);
                else outf[(size_t)r0 * DOUT + col] = h;
            }
        }
    }
}

// ---------------- pooling ----------------

__global__ __launch_bounds__(256) void k_pool(const float* __restrict__ x3,
                                              const int* __restrict__ gstart,
                                              float* __restrict__ pooled, int G) {
    const int S = 16;
    int g = blockIdx.x / S;
    int s = blockIdx.x % S;
    int a = gstart[g], b = gstart[g + 1];
    int col = threadIdx.x;
    float acc = 0.f;
    for (int r = a + s; r < b; r += S) acc += x3[(size_t)r * 256 + col];
    atomicAdd(&pooled[g * 256 + col], acc);
}

// ---------------- launch ----------------

extern "C" void kernel_launch(void* const* d_in, const int* in_sizes, int n_in,
                              void* d_out, int out_size, void* d_ws, size_t ws_size,
                              hipStream_t stream) {
    const float* x = (const float*)d_in[0];
    const int* ei = (const int*)d_in[1];
    const int* batch = (const int*)d_in[2];
    const int N = in_sizes[0] / 7;
    const int E = in_sizes[1] / 2;
    const int G = 64;
    const int* src = ei;
    const int* dst = ei + E;
    const int NPART = (N + PMASK) >> PSHIFT;
    const int NB1 = (N + (1 << B1SHIFT) - 1) >> B1SHIFT;

    const float* P[21];
    for (int i = 0; i < 21; i++) P[i] = (const float*)d_in[3 + i];
    const float **L0 = P, **L1 = P + 7, **L2 = P + 14;

    char* w = (char*)d_ws;
    auto carve = [&](size_t bytes) {
        void* p = (void*)w;
        w += (bytes + 255) & ~(size_t)255;
        return p;
    };
    int* cnts = (int*)carve((size_t)(64 + NPART) * 4);  // bcnt1[64] + pcnt[NPART]
    int* bcnt1 = cnts;
    int* pcnt = cnts + 64;
    unsigned* stg1 = (unsigned*)carve((size_t)NB1 * B1CAP * 4);
    unsigned* pstg = (unsigned*)carve((size_t)NPART * PCAP * 4);
    int* pbase = (int*)carve((size_t)NPART * 4);
    int* off = (int*)carve(((size_t)N + 1) * 4);
    int* gstart = (int*)carve(((size_t)G + 1) * 4);
    float* mean7 = (float*)carve((size_t)N * 7 * 4);
    unsigned short* x1 = (unsigned short*)carve((size_t)N * 128 * 2);
    unsigned short* meanb = (unsigned short*)carve((size_t)N * 128 * 2);
    unsigned short* Wlt1 = (unsigned short*)carve((size_t)128 * 128 * 2);
    unsigned short* Wrt1 = (unsigned short*)carve((size_t)128 * 128 * 2);
    unsigned short* Wlt2 = (unsigned short*)carve((size_t)128 * 256 * 2);
    unsigned short* Wrt2 = (unsigned short*)carve((size_t)128 * 256 * 2);
    // csr aliases stg1: stg1 is dead after k_scatter2 completes, and k_build
    // (same stream) is the first writer of csr.
    int* csr = (int*)stg1;

    float* pooled = (float*)d_out;
    float* x3 = (float*)d_out + (size_t)G * 256;

    hipMemsetAsync(cnts, 0, (size_t)(64 + NPART) * 4, stream);
    hipMemsetAsync(pooled, 0, (size_t)G * 256 * 4, stream);

    // CSR build: two-level LDS-ranked scatter + meta + partition sort
    k_scatter1<<<(E + 2047) / 2048, 256, 0, stream>>>(src, dst, bcnt1, stg1, E, NB1);
    k_scatter2<<<NB1 * SPLIT, 256, 0, stream>>>(bcnt1, stg1, pcnt, pstg);
    k_meta<<<2, 256, 0, stream>>>(pcnt, pbase, off, batch, gstart, NPART, N, G);
    k_build<<<NPART, 256, 0, stream>>>(pcnt, pstg, pbase, off, csr, N);
    k_prepw_all<<<(98304 + 255) / 256, 256, 0, stream>>>(L1[0], L1[2], L2[0], L2[2],
                                                         Wlt1, Wrt1, Wlt2, Wrt2);

    // layer 0: din=7 -> 128 (fp32 vector, bf16 out)
    k_agg7<<<(N * 8 + 255) / 256, 256, 0, stream>>>(x, off, csr, mean7, N);
    k_layer0<<<(N + 1) / 2, 256, 0, stream>>>(x, mean7, L0[0], L0[1], L0[2], L0[3],
                                              L0[4], L0[5], L0[6], x1, N);

    // layer 1: 128 -> 128, MFMA, in-place on x1 (full-width blocks own their rows)
    k_agg128<<<(N + 7) / 8, 256, 0, stream>>>(x1, off, csr, meanb, N);
    k_mfma_layer<128, 128, true><<<dim3((N + 63) / 64, 1), 256, 0, stream>>>(
        x1, meanb, Wlt1, Wrt1, L1[1], L1[3], L1[4], L1[5], L1[6], x1, N);

    // layer 2: 128 -> 256, MFMA, fp32 out into d_out x-region
    k_agg128<<<(N + 7) / 8, 256, 0, stream>>>(x1, off, csr, meanb, N);
    k_mfma_layer<128, 256, false><<<dim3((N + 63) / 64, 2), 256, 0, stream>>>(
        x1, meanb, Wlt2, Wrt2, L2[1], L2[3], L2[4], L2[5], L2[6], x3, N);

    // global add pool
    k_pool<<<G * 16, 256, 0, stream>>>(x3, gstart, pooled, G);
}